// Round 2
// baseline (245.161 us; speedup 1.0000x reference)
//
#include <hip/hip_runtime.h>
#include <hip/hip_bf16.h>

// OPT attention: B=16 T=4 E=2048 H=32 HD=64 P=4096 S=4100, M=B*T=64 rows.
// All GEMM-shaped work on mfma_f32_16x16x32_bf16 (A[m=lane&15][k=quad*8+j],
// B[n=lane&15][k=quad*8+j], D col=lane&15 row=quad*4+reg — verified layouts).
// Output dtype: FLOAT32 (reference returns f32).
//
// R3: structural round. k_qkv+k_qkv_red fused into one full-K no-LDS kernel
// (direct global A/B fragments, hs L2-resident, dual accumulators, fused
// bias/scale/layout epilogue). k_out staging removed (attn bf16 read direct),
// split-K 8->2, vectorized reduce. k_merge wave-parallel over tt. 6->5 kernels,
// ~19MB of partial round-trip HBM traffic removed.

typedef float f4 __attribute__((ext_vector_type(4)));
typedef short s8v __attribute__((ext_vector_type(8)));

#define NEG_HUGE (-3.402823466e38f)

__device__ inline unsigned short f2bs(float x) {  // f32 -> bf16 bits (RNE)
  union { float f; unsigned int u; } a; a.f = x;
  unsigned int u = a.u;
  u += 0x7fffu + ((u >> 16) & 1u);
  return (unsigned short)(u >> 16);
}
__device__ inline float bs2f(unsigned short s) {
  union { unsigned int u; float f; } a; a.u = ((unsigned int)s) << 16;
  return a.f;
}
__device__ inline unsigned int pk2(float a, float b) {  // packed RNE cvt
  union { __hip_bfloat162 v; unsigned int u; } c;
  c.v = __float22bfloat162_rn(make_float2(a, b));
  return c.u;
}
__device__ inline s8v cvt8(f4 a, f4 b) {
  union { s8v s; unsigned int u[4]; } r;
  r.u[0] = pk2(a[0], a[1]); r.u[1] = pk2(a[2], a[3]);
  r.u[2] = pk2(b[0], b[1]); r.u[3] = pk2(b[2], b[3]);
  return r.s;
}
__device__ inline f4 mfma16(s8v a, s8v b, f4 c) {
  return __builtin_amdgcn_mfma_f32_16x16x32_bf16(a, b, c, 0, 0, 0);
}
__device__ inline f4 fzero() { f4 z = {0.f,0.f,0.f,0.f}; return z; }
__device__ inline float wave_sum(float v) {
  #pragma unroll
  for (int off = 32; off; off >>= 1) v += __shfl_xor(v, off, 64);
  return v;
}

// ---------- Kernel 1: fused QKV projection (full-K, no LDS, no split) --------
// grid 384: block = 16 output cols (n0) x all 64 rows; wave w = m-tile w.
// A (hs) and B (W) fragments straight from global; hs is 512KB -> L2-resident.
__global__ __launch_bounds__(256) void k_qkv_f(
    const float* __restrict__ hs, const float* __restrict__ Wq,
    const float* __restrict__ Wk, const float* __restrict__ Wv,
    const float* __restrict__ bq, const float* __restrict__ bk,
    const float* __restrict__ bv,
    unsigned short* __restrict__ qws, float* __restrict__ knew,
    float* __restrict__ vnew) {
  const int n0 = blockIdx.x * 16;          // 0..6128
  const int p = n0 >> 11;                  // 0=Q 1=K 2=V (block-uniform)
  const int c0 = n0 & 2047;                // col within projection
  const float* W = (p == 0) ? Wq : (p == 1) ? Wk : Wv;
  const int t = threadIdx.x, lane = t & 63, w = t >> 6;
  const int cl = lane & 15, quad = lane >> 4;

  const float* arow = hs + (size_t)(w * 16 + cl) * 2048 + quad * 8;
  const float* brow = W + (size_t)(c0 + cl) * 2048 + quad * 8;

  f4 acc0 = fzero(), acc1 = fzero();       // dual accumulators (ILP 2)
  #pragma unroll 4
  for (int ks = 0; ks < 64; ks += 2) {
    f4 a0 = *reinterpret_cast<const f4*>(arow + ks * 32);
    f4 a1 = *reinterpret_cast<const f4*>(arow + ks * 32 + 4);
    f4 b0 = *reinterpret_cast<const f4*>(brow + ks * 32);
    f4 b1 = *reinterpret_cast<const f4*>(brow + ks * 32 + 4);
    acc0 = mfma16(cvt8(a0, a1), cvt8(b0, b1), acc0);
    f4 a2 = *reinterpret_cast<const f4*>(arow + ks * 32 + 32);
    f4 a3 = *reinterpret_cast<const f4*>(arow + ks * 32 + 36);
    f4 b2 = *reinterpret_cast<const f4*>(brow + ks * 32 + 32);
    f4 b3 = *reinterpret_cast<const f4*>(brow + ks * 32 + 36);
    acc1 = mfma16(cvt8(a2, a3), cvt8(b2, b3), acc1);
  }

  const int n = c0 + cl;                   // col within projection
  const int h = n >> 6, d = n & 63;
  const float bias = (p == 0) ? bq[n] : (p == 1) ? bk[n] : bv[n];
  #pragma unroll
  for (int rg = 0; rg < 4; ++rg) {
    const int r = w * 16 + quad * 4 + rg;  // output row (b*4+tt)
    const int b = r >> 2, tt = r & 3;
    float s = acc0[rg] + acc1[rg] + bias;
    if (p == 0) {
      qws[h * 4608 + r * 72 + d] = f2bs(s * 0.125f);   // query pre-scale
    } else if (p == 1) {
      knew[((h * 16 + b) * 4 + tt) * 64 + d] = s;
    } else {
      vnew[((h * 16 + b) * 4 + tt) * 64 + d] = s;
    }
  }
}

// --------- Kernel 2: flash partial attention over past KV chunks -------------
// grid 512: h = bx&31, chunk = bx>>5 (256 past positions each)
// Swapped QK^T: acc = mfma(K_frag, Q_frag) -> D[m=s][n=q]; per lane:
// s = w*64 + si*16 + quad*4 + rg (register dims), q = qt*16 + cl (lane dim).
__global__ __launch_bounds__(256) void k_flash(
    const unsigned short* __restrict__ qws, const float* __restrict__ Kp,
    const float* __restrict__ Vp, const float* __restrict__ mask,
    float* __restrict__ Opart, float* __restrict__ mpart,
    float* __restrict__ lpart) {
  __shared__ __align__(16) unsigned short Pl[64 * 264];  // P[q][s] bf16
  __shared__ float redm[4 * 64];
  __shared__ float reds[4 * 64];
  const int bx = blockIdx.x;
  const int h = bx & 31, cch = bx >> 5;
  const int s0 = cch * 256;
  const int t = threadIdx.x, lane = t & 63, w = t >> 6;
  const int cl = lane & 15, quad = lane >> 4;
  const float* Kh = Kp + (size_t)h * 4096 * 64;
  const float* Vh = Vp + (size_t)h * 4096 * 64;

  // Q fragments direct from global (qws is 288 KB total -> L2-resident)
  s8v qf[4][2];
  #pragma unroll
  for (int qt = 0; qt < 4; ++qt)
    #pragma unroll
    for (int k2 = 0; k2 < 2; ++k2)
      qf[qt][k2] = *reinterpret_cast<const s8v*>(
          qws + h * 4608 + (qt * 16 + cl) * 72 + k2 * 32 + quad * 8);

  // QK^T (swapped): acc[si][qt]
  f4 acc[4][4];
  #pragma unroll
  for (int si = 0; si < 4; ++si)
    #pragma unroll
    for (int qt = 0; qt < 4; ++qt) acc[si][qt] = fzero();

  #pragma unroll
  for (int si = 0; si < 4; ++si) {
    const float* kr = Kh + (size_t)(s0 + w * 64 + si * 16 + cl) * 64 + quad * 8;
    #pragma unroll
    for (int k2 = 0; k2 < 2; ++k2) {
      f4 k0v = *reinterpret_cast<const f4*>(kr + k2 * 32);
      f4 k1v = *reinterpret_cast<const f4*>(kr + k2 * 32 + 4);
      s8v ak = cvt8(k0v, k1v);
      #pragma unroll
      for (int qt = 0; qt < 4; ++qt)
        acc[si][qt] = mfma16(ak, qf[qt][k2], acc[si][qt]);
    }
  }

  // mask add + clamp (rg dim == consecutive s -> vector f4 loads)
  #pragma unroll
  for (int si = 0; si < 4; ++si)
    #pragma unroll
    for (int qt = 0; qt < 4; ++qt) {
      f4 mv = *reinterpret_cast<const f4*>(
          mask + (size_t)(qt * 16 + cl) * 4100 + s0 + w * 64 + si * 16 + quad * 4);
      #pragma unroll
      for (int rg = 0; rg < 4; ++rg)
        acc[si][qt][rg] = fmaxf(acc[si][qt][rg] + mv[rg], NEG_HUGE);
    }

  // per-q max over this wave's 64 s: 15 in-reg max + shfl_xor(16,32)
  #pragma unroll
  for (int qt = 0; qt < 4; ++qt) {
    float m = NEG_HUGE;
    #pragma unroll
    for (int si = 0; si < 4; ++si)
      #pragma unroll
      for (int rg = 0; rg < 4; ++rg) m = fmaxf(m, acc[si][qt][rg]);
    m = fmaxf(m, __shfl_xor(m, 16, 64));
    m = fmaxf(m, __shfl_xor(m, 32, 64));
    if (quad == 0) redm[w * 64 + qt * 16 + cl] = m;
  }
  __syncthreads();

  // chunk-global per-q max (broadcast reads), exp, sum, pack P -> LDS bf16
  float mq[4];
  #pragma unroll
  for (int qt = 0; qt < 4; ++qt) {
    int q = qt * 16 + cl;
    mq[qt] = fmaxf(fmaxf(redm[q], redm[64 + q]),
                   fmaxf(redm[128 + q], redm[192 + q]));
    if (w == 0 && quad == 0) mpart[(h * 16 + cch) * 64 + q] = mq[qt];
  }
  #pragma unroll
  for (int qt = 0; qt < 4; ++qt) {
    float sum = 0.f;
    #pragma unroll
    for (int si = 0; si < 4; ++si) {
      f4 e;
      #pragma unroll
      for (int rg = 0; rg < 4; ++rg) {
        e[rg] = __expf(acc[si][qt][rg] - mq[qt]);
        sum += e[rg];
      }
      uint2 pw;
      pw.x = pk2(e[0], e[1]);
      pw.y = pk2(e[2], e[3]);
      *reinterpret_cast<uint2*>(
          &Pl[(qt * 16 + cl) * 264 + w * 64 + si * 16 + quad * 4]) = pw;
    }
    sum += __shfl_xor(sum, 16, 64);
    sum += __shfl_xor(sum, 32, 64);
    if (quad == 0) reds[w * 64 + qt * 16 + cl] = sum;
  }
  __syncthreads();

  if (w == 0 && quad == 0) {
    #pragma unroll
    for (int qt = 0; qt < 4; ++qt) {
      int q = qt * 16 + cl;
      lpart[(h * 16 + cch) * 64 + q] =
          reds[q] + reds[64 + q] + reds[128 + q] + reds[192 + q];
    }
  }

  // PV: wave w owns d-tile w (cols w*16..w*16+15); A = P (from Pl), B = V
  f4 oacc[4];
  #pragma unroll
  for (int mt = 0; mt < 4; ++mt) oacc[mt] = fzero();
  const int dcol = w * 16 + cl;
  #pragma unroll
  for (int k2 = 0; k2 < 8; ++k2) {
    const int sb = k2 * 32 + quad * 8;
    const float* vb = Vh + (size_t)(s0 + sb) * 64 + dcol;
    f4 v0, v1;
    v0[0] = vb[0];   v0[1] = vb[64];  v0[2] = vb[128]; v0[3] = vb[192];
    v1[0] = vb[256]; v1[1] = vb[320]; v1[2] = vb[384]; v1[3] = vb[448];
    s8v bvv = cvt8(v0, v1);
    #pragma unroll
    for (int mt = 0; mt < 4; ++mt) {
      s8v pa = *reinterpret_cast<const s8v*>(&Pl[(mt * 16 + cl) * 264 + sb]);
      oacc[mt] = mfma16(pa, bvv, oacc[mt]);
    }
  }
  float* ob = Opart + (size_t)(h * 16 + cch) * 64 * 64;
  #pragma unroll
  for (int mt = 0; mt < 4; ++mt)
    #pragma unroll
    for (int rg = 0; rg < 4; ++rg)
      ob[(mt * 16 + quad * 4 + rg) * 64 + dcol] = oacc[mt][rg];
}

// ------- Kernel 3: merge chunk partials + 4 new-token scores per (b,h) -------
// grid 512 x 256 threads: block = (h,b), wave = tt (wave-parallel merge).
__global__ __launch_bounds__(256) void k_merge(
    const unsigned short* __restrict__ qws, const float* __restrict__ knew,
    const float* __restrict__ vnew, const float* __restrict__ mask,
    const float* __restrict__ Opart, const float* __restrict__ mpart,
    const float* __restrict__ lpart, unsigned short* __restrict__ attn) {
  const int bx = blockIdx.x;
  const int h = bx & 31, b = bx >> 5;
  const int tt = threadIdx.x >> 6;
  const int d = threadIdx.x & 63;
  const int r = b * 4 + tt;
  float qd = bs2f(qws[h * 4608 + r * 72 + d]);
  float scn[4];
  #pragma unroll
  for (int tp = 0; tp < 4; ++tp) {
    float kn = knew[((h * 16 + b) * 4 + tp) * 64 + d];
    float s = wave_sum(qd * kn);
    s += mask[(size_t)r * 4100 + 4096 + tp];
    scn[tp] = fmaxf(s, NEG_HUGE);
  }
  float mi[16], li[16];
  float mtot = NEG_HUGE;
  #pragma unroll
  for (int i = 0; i < 16; ++i) {
    mi[i] = mpart[(h * 16 + i) * 64 + r];
    li[i] = lpart[(h * 16 + i) * 64 + r];
    mtot = fmaxf(mtot, mi[i]);
  }
  #pragma unroll
  for (int tp = 0; tp < 4; ++tp) mtot = fmaxf(mtot, scn[tp]);
  float ltot = 0.f, od = 0.f;
  #pragma unroll
  for (int i = 0; i < 16; ++i) {
    float fct = __expf(mi[i] - mtot);
    ltot += li[i] * fct;
    od += Opart[((size_t)(h * 16 + i) * 64 + r) * 64 + d] * fct;
  }
  #pragma unroll
  for (int tp = 0; tp < 4; ++tp) {
    float e = __expf(scn[tp] - mtot);
    ltot += e;
    od += e * vnew[((h * 16 + b) * 4 + tp) * 64 + d];
  }
  attn[(size_t)r * 2048 + h * 64 + d] = f2bs(od / ltot);
}

// -------- Kernel 4: output projection (no LDS, direct bf16 A, split-K2) ------
// grid (128, 2): x = 16-col tile, y = k-half (1024 each); wave w = m-tile w.
__global__ __launch_bounds__(256) void k_out(
    const unsigned short* __restrict__ attn, const float* __restrict__ Wo,
    float* __restrict__ part) {
  const int n0 = blockIdx.x * 16;
  const int k0 = blockIdx.y * 1024;
  const int t = threadIdx.x, lane = t & 63, w = t >> 6;
  const int cl = lane & 15, quad = lane >> 4;
  const unsigned short* arow = attn + (size_t)(w * 16 + cl) * 2048 + k0 + quad * 8;
  const float* brow = Wo + (size_t)(n0 + cl) * 2048 + k0 + quad * 8;
  f4 acc0 = fzero(), acc1 = fzero();
  #pragma unroll 4
  for (int ks = 0; ks < 32; ks += 2) {
    s8v a0 = *reinterpret_cast<const s8v*>(arow + ks * 32);
    f4 b0 = *reinterpret_cast<const f4*>(brow + ks * 32);
    f4 b1 = *reinterpret_cast<const f4*>(brow + ks * 32 + 4);
    acc0 = mfma16(a0, cvt8(b0, b1), acc0);
    s8v a1 = *reinterpret_cast<const s8v*>(arow + ks * 32 + 32);
    f4 b2 = *reinterpret_cast<const f4*>(brow + ks * 32 + 32);
    f4 b3 = *reinterpret_cast<const f4*>(brow + ks * 32 + 36);
    acc1 = mfma16(a1, cvt8(b2, b3), acc1);
  }
  float* op = part + (size_t)blockIdx.y * 131072;
  #pragma unroll
  for (int rg = 0; rg < 4; ++rg) {
    const int r = w * 16 + quad * 4 + rg;
    op[r * 2048 + n0 + cl] = acc0[rg] + acc1[rg];
  }
}

// ----------------- Kernel 5: reduce + bias -> f32 output ---------------------
__global__ __launch_bounds__(256) void k_out_red(
    const float* __restrict__ part, const float* __restrict__ bo,
    float* __restrict__ out) {
  const int i4 = blockIdx.x * 256 + threadIdx.x;   // < 32768 float4s
  f4 a = *reinterpret_cast<const f4*>(part + (size_t)i4 * 4);
  f4 b = *reinterpret_cast<const f4*>(part + 131072 + (size_t)i4 * 4);
  f4 bias = *reinterpret_cast<const f4*>(bo + (i4 & 511) * 4);
  f4 o;
  #pragma unroll
  for (int rg = 0; rg < 4; ++rg) o[rg] = a[rg] + b[rg] + bias[rg];
  *reinterpret_cast<f4*>(out + (size_t)i4 * 4) = o;
}

extern "C" void kernel_launch(void* const* d_in, const int* in_sizes, int n_in,
                              void* d_out, int out_size, void* d_ws, size_t ws_size,
                              hipStream_t stream) {
  const float* hs   = (const float*)d_in[0];
  const float* pk   = (const float*)d_in[1];
  const float* pv   = (const float*)d_in[2];
  const float* mask = (const float*)d_in[3];
  const float* Wq   = (const float*)d_in[4];
  const float* bq   = (const float*)d_in[5];
  const float* Wk   = (const float*)d_in[6];
  const float* bk   = (const float*)d_in[7];
  const float* Wv   = (const float*)d_in[8];
  const float* bv   = (const float*)d_in[9];
  const float* Wo   = (const float*)d_in[10];
  const float* bo   = (const float*)d_in[11];

  float* f = (float*)d_ws;
  float* o_part = f;                          // [2][64][2048]
  float* Opart  = o_part + 262144;            // [32][16][64][64]
  float* mpart  = Opart  + 2097152;           // [32][16][64]
  float* lpart  = mpart  + 32768;
  float* knew   = lpart  + 32768;             // [32][16][4][64]
  float* vnew   = knew   + 131072;
  unsigned short* qws  = (unsigned short*)(vnew + 131072);  // [32][64][72] bf16
  unsigned short* attn = qws + 147456;                      // [64][2048] bf16

  k_qkv_f<<<384, 256, 0, stream>>>(hs, Wq, Wk, Wv, bq, bk, bv, qws, knew, vnew);
  k_flash<<<512, 256, 0, stream>>>(qws, pk, pv, mask, Opart, mpart, lpart);
  k_merge<<<512, 256, 0, stream>>>(qws, knew, vnew, mask, Opart, mpart, lpart, attn);
  k_out<<<dim3(128, 2), 256, 0, stream>>>(attn, Wo, o_part);
  k_out_red<<<128, 256, 0, stream>>>(o_part, bo, (float*)d_out);
}

// Round 3
// 196.564 us; speedup vs baseline: 1.2472x; 1.2472x over previous
//
#include <hip/hip_runtime.h>
#include <hip/hip_bf16.h>

// OPT attention: B=16 T=4 E=2048 H=32 HD=64 P=4096 S=4100, M=B*T=64 rows.
// All GEMM-shaped work on mfma_f32_16x16x32_bf16 (A[m=lane&15][k=quad*8+j],
// B[n=lane&15][k=quad*8+j], D col=lane&15 row=quad*4+reg — verified layouts).
// Output dtype: FLOAT32 (reference returns f32).
//
// R4: revert R3's latency-bound fused QKV (62us, 465GB/s, 1.5 waves/SIMD) back
// to LDS-staged split-K, deepened to ksplit=8 (768 blocks, 3/CU). Vectorized
// f4 reduce kernels. k_out back to LDS-staged (32,8). flash/merge from R3.

typedef float f4 __attribute__((ext_vector_type(4)));
typedef short s8v __attribute__((ext_vector_type(8)));

#define NEG_HUGE (-3.402823466e38f)

__device__ inline unsigned short f2bs(float x) {  // f32 -> bf16 bits (RNE)
  union { float f; unsigned int u; } a; a.f = x;
  unsigned int u = a.u;
  u += 0x7fffu + ((u >> 16) & 1u);
  return (unsigned short)(u >> 16);
}
__device__ inline float bs2f(unsigned short s) {
  union { unsigned int u; float f; } a; a.u = ((unsigned int)s) << 16;
  return a.f;
}
__device__ inline unsigned int pk2(float a, float b) {  // packed RNE cvt
  union { __hip_bfloat162 v; unsigned int u; } c;
  c.v = __float22bfloat162_rn(make_float2(a, b));
  return c.u;
}
__device__ inline unsigned long long pack4(float a, float b, float c, float d) {
  return (unsigned long long)pk2(a, b) | ((unsigned long long)pk2(c, d) << 32);
}
__device__ inline s8v cvt8(f4 a, f4 b) {
  union { s8v s; unsigned int u[4]; } r;
  r.u[0] = pk2(a[0], a[1]); r.u[1] = pk2(a[2], a[3]);
  r.u[2] = pk2(b[0], b[1]); r.u[3] = pk2(b[2], b[3]);
  return r.s;
}
__device__ inline f4 mfma16(s8v a, s8v b, f4 c) {
  return __builtin_amdgcn_mfma_f32_16x16x32_bf16(a, b, c, 0, 0, 0);
}
__device__ inline f4 fzero() { f4 z = {0.f,0.f,0.f,0.f}; return z; }
__device__ inline float wave_sum(float v) {
  #pragma unroll
  for (int off = 32; off; off >>= 1) v += __shfl_xor(v, off, 64);
  return v;
}

// ---------------- Kernel 1: QKV projection, split-K partials -----------------
// grid (96, 8): x = 64-col block over N=3*2048, y = k-split (256 k each).
// LDS-staged A tile (latency hiding), 3 blocks/CU, 4 indep MFMA chains/wave.
__global__ __launch_bounds__(256) void k_qkv(
    const float* __restrict__ hs, const float* __restrict__ Wq,
    const float* __restrict__ Wk, const float* __restrict__ Wv,
    float* __restrict__ part) {
  __shared__ __align__(16) unsigned short As[64 * 264];
  const int n0 = blockIdx.x * 64;
  const int k0 = blockIdx.y * 256;
  const int p = n0 >> 11;
  const int c0 = n0 & 2047;
  const float* W = (p == 0) ? Wq : (p == 1) ? Wk : Wv;
  const int t = threadIdx.x, lane = t & 63, w = t >> 6;
  const int cl = lane & 15, quad = lane >> 4;

  // stage A tile [64][256] f32 -> bf16 LDS (row stride 264 breaks conflicts)
  #pragma unroll
  for (int i = 0; i < 16; ++i) {
    int idx4 = t + (i << 8);          // 0..4095 float4s
    int row = idx4 >> 6;
    int col = (idx4 & 63) << 2;
    f4 v = *reinterpret_cast<const f4*>(hs + row * 2048 + k0 + col);
    *reinterpret_cast<unsigned long long*>(&As[row * 264 + col]) =
        pack4(v[0], v[1], v[2], v[3]);
  }
  __syncthreads();

  f4 acc[4];
  #pragma unroll
  for (int i = 0; i < 4; ++i) acc[i] = fzero();

  const int cw = c0 + w * 16 + cl;  // W row (output col within projection)
  const float* wbase = W + (size_t)cw * 2048 + k0;
  #pragma unroll
  for (int ks2 = 0; ks2 < 8; ++ks2) {
    const int kb = ks2 * 32 + quad * 8;
    f4 w0 = *reinterpret_cast<const f4*>(wbase + kb);
    f4 w1 = *reinterpret_cast<const f4*>(wbase + kb + 4);
    s8v bf = cvt8(w0, w1);
    #pragma unroll
    for (int mt = 0; mt < 4; ++mt) {
      s8v af = *reinterpret_cast<const s8v*>(&As[(mt * 16 + cl) * 264 + kb]);
      acc[mt] = mfma16(af, bf, acc[mt]);
    }
  }
  float* outp = part + (size_t)blockIdx.y * 64 * 6144;
  #pragma unroll
  for (int mt = 0; mt < 4; ++mt)
    #pragma unroll
    for (int rg = 0; rg < 4; ++rg) {
      int r = mt * 16 + quad * 4 + rg;
      outp[r * 6144 + n0 + w * 16 + cl] = acc[mt][rg];
    }
}

// ------- Kernel 2: reduce 8 partials + bias, layout q/k/v (vectorized) -------
__global__ __launch_bounds__(256) void k_qkv_red(
    const float* __restrict__ part, const float* __restrict__ bq,
    const float* __restrict__ bk, const float* __restrict__ bv,
    unsigned short* __restrict__ qws, float* __restrict__ knew,
    float* __restrict__ vnew) {
  const int i4 = blockIdx.x * 256 + threadIdx.x;   // < 98304
  const int base = i4 * 4;
  const int r = base / 6144;
  const int n = base - r * 6144;                   // multiple of 4
  f4 s = *reinterpret_cast<const f4*>(part + base);
  #pragma unroll
  for (int ks = 1; ks < 8; ++ks) {
    f4 p2 = *reinterpret_cast<const f4*>(part + (size_t)ks * 393216 + base);
    #pragma unroll
    for (int j = 0; j < 4; ++j) s[j] += p2[j];
  }
  const int p = n >> 11, c = n & 2047;
  const int h = c >> 6, d = c & 63;
  const int b = r >> 2, tt = r & 3;
  if (p == 0) {
    f4 bb = *reinterpret_cast<const f4*>(bq + c);
    uint2 pw;
    pw.x = pk2((s[0] + bb[0]) * 0.125f, (s[1] + bb[1]) * 0.125f);
    pw.y = pk2((s[2] + bb[2]) * 0.125f, (s[3] + bb[3]) * 0.125f);
    *reinterpret_cast<uint2*>(qws + h * 4608 + r * 72 + d) = pw;
  } else if (p == 1) {
    f4 bb = *reinterpret_cast<const f4*>(bk + c);
    f4 o;
    #pragma unroll
    for (int j = 0; j < 4; ++j) o[j] = s[j] + bb[j];
    *reinterpret_cast<f4*>(knew + ((h * 16 + b) * 4 + tt) * 64 + d) = o;
  } else {
    f4 bb = *reinterpret_cast<const f4*>(bv + c);
    f4 o;
    #pragma unroll
    for (int j = 0; j < 4; ++j) o[j] = s[j] + bb[j];
    *reinterpret_cast<f4*>(vnew + ((h * 16 + b) * 4 + tt) * 64 + d) = o;
  }
}

// --------- Kernel 3: flash partial attention over past KV chunks -------------
// grid 512: h = bx&31, chunk = bx>>5 (256 past positions each)
// Swapped QK^T: acc = mfma(K_frag, Q_frag) -> D[m=s][n=q]; per lane:
// s = w*64 + si*16 + quad*4 + rg (register dims), q = qt*16 + cl (lane dim).
__global__ __launch_bounds__(256) void k_flash(
    const unsigned short* __restrict__ qws, const float* __restrict__ Kp,
    const float* __restrict__ Vp, const float* __restrict__ mask,
    float* __restrict__ Opart, float* __restrict__ mpart,
    float* __restrict__ lpart) {
  __shared__ __align__(16) unsigned short Pl[64 * 264];  // P[q][s] bf16
  __shared__ float redm[4 * 64];
  __shared__ float reds[4 * 64];
  const int bx = blockIdx.x;
  const int h = bx & 31, cch = bx >> 5;
  const int s0 = cch * 256;
  const int t = threadIdx.x, lane = t & 63, w = t >> 6;
  const int cl = lane & 15, quad = lane >> 4;
  const float* Kh = Kp + (size_t)h * 4096 * 64;
  const float* Vh = Vp + (size_t)h * 4096 * 64;

  // Q fragments direct from global (qws is 288 KB total -> L2-resident)
  s8v qf[4][2];
  #pragma unroll
  for (int qt = 0; qt < 4; ++qt)
    #pragma unroll
    for (int k2 = 0; k2 < 2; ++k2)
      qf[qt][k2] = *reinterpret_cast<const s8v*>(
          qws + h * 4608 + (qt * 16 + cl) * 72 + k2 * 32 + quad * 8);

  // QK^T (swapped): acc[si][qt]
  f4 acc[4][4];
  #pragma unroll
  for (int si = 0; si < 4; ++si)
    #pragma unroll
    for (int qt = 0; qt < 4; ++qt) acc[si][qt] = fzero();

  #pragma unroll
  for (int si = 0; si < 4; ++si) {
    const float* kr = Kh + (size_t)(s0 + w * 64 + si * 16 + cl) * 64 + quad * 8;
    #pragma unroll
    for (int k2 = 0; k2 < 2; ++k2) {
      f4 k0v = *reinterpret_cast<const f4*>(kr + k2 * 32);
      f4 k1v = *reinterpret_cast<const f4*>(kr + k2 * 32 + 4);
      s8v ak = cvt8(k0v, k1v);
      #pragma unroll
      for (int qt = 0; qt < 4; ++qt)
        acc[si][qt] = mfma16(ak, qf[qt][k2], acc[si][qt]);
    }
  }

  // mask add + clamp (rg dim == consecutive s -> vector f4 loads)
  #pragma unroll
  for (int si = 0; si < 4; ++si)
    #pragma unroll
    for (int qt = 0; qt < 4; ++qt) {
      f4 mv = *reinterpret_cast<const f4*>(
          mask + (size_t)(qt * 16 + cl) * 4100 + s0 + w * 64 + si * 16 + quad * 4);
      #pragma unroll
      for (int rg = 0; rg < 4; ++rg)
        acc[si][qt][rg] = fmaxf(acc[si][qt][rg] + mv[rg], NEG_HUGE);
    }

  // per-q max over this wave's 64 s: 15 in-reg max + shfl_xor(16,32)
  #pragma unroll
  for (int qt = 0; qt < 4; ++qt) {
    float m = NEG_HUGE;
    #pragma unroll
    for (int si = 0; si < 4; ++si)
      #pragma unroll
      for (int rg = 0; rg < 4; ++rg) m = fmaxf(m, acc[si][qt][rg]);
    m = fmaxf(m, __shfl_xor(m, 16, 64));
    m = fmaxf(m, __shfl_xor(m, 32, 64));
    if (quad == 0) redm[w * 64 + qt * 16 + cl] = m;
  }
  __syncthreads();

  // chunk-global per-q max (broadcast reads), exp, sum, pack P -> LDS bf16
  float mq[4];
  #pragma unroll
  for (int qt = 0; qt < 4; ++qt) {
    int q = qt * 16 + cl;
    mq[qt] = fmaxf(fmaxf(redm[q], redm[64 + q]),
                   fmaxf(redm[128 + q], redm[192 + q]));
    if (w == 0 && quad == 0) mpart[(h * 16 + cch) * 64 + q] = mq[qt];
  }
  #pragma unroll
  for (int qt = 0; qt < 4; ++qt) {
    float sum = 0.f;
    #pragma unroll
    for (int si = 0; si < 4; ++si) {
      f4 e;
      #pragma unroll
      for (int rg = 0; rg < 4; ++rg) {
        e[rg] = __expf(acc[si][qt][rg] - mq[qt]);
        sum += e[rg];
      }
      uint2 pw;
      pw.x = pk2(e[0], e[1]);
      pw.y = pk2(e[2], e[3]);
      *reinterpret_cast<uint2*>(
          &Pl[(qt * 16 + cl) * 264 + w * 64 + si * 16 + quad * 4]) = pw;
    }
    sum += __shfl_xor(sum, 16, 64);
    sum += __shfl_xor(sum, 32, 64);
    if (quad == 0) reds[w * 64 + qt * 16 + cl] = sum;
  }
  __syncthreads();

  if (w == 0 && quad == 0) {
    #pragma unroll
    for (int qt = 0; qt < 4; ++qt) {
      int q = qt * 16 + cl;
      lpart[(h * 16 + cch) * 64 + q] =
          reds[q] + reds[64 + q] + reds[128 + q] + reds[192 + q];
    }
  }

  // PV: wave w owns d-tile w (cols w*16..w*16+15); A = P (from Pl), B = V
  f4 oacc[4];
  #pragma unroll
  for (int mt = 0; mt < 4; ++mt) oacc[mt] = fzero();
  const int dcol = w * 16 + cl;
  #pragma unroll
  for (int k2 = 0; k2 < 8; ++k2) {
    const int sb = k2 * 32 + quad * 8;
    const float* vb = Vh + (size_t)(s0 + sb) * 64 + dcol;
    f4 v0, v1;
    v0[0] = vb[0];   v0[1] = vb[64];  v0[2] = vb[128]; v0[3] = vb[192];
    v1[0] = vb[256]; v1[1] = vb[320]; v1[2] = vb[384]; v1[3] = vb[448];
    s8v bvv = cvt8(v0, v1);
    #pragma unroll
    for (int mt = 0; mt < 4; ++mt) {
      s8v pa = *reinterpret_cast<const s8v*>(&Pl[(mt * 16 + cl) * 264 + sb]);
      oacc[mt] = mfma16(pa, bvv, oacc[mt]);
    }
  }
  float* ob = Opart + (size_t)(h * 16 + cch) * 64 * 64;
  #pragma unroll
  for (int mt = 0; mt < 4; ++mt)
    #pragma unroll
    for (int rg = 0; rg < 4; ++rg)
      ob[(mt * 16 + quad * 4 + rg) * 64 + dcol] = oacc[mt][rg];
}

// ------- Kernel 4: merge chunk partials + 4 new-token scores per (b,h) -------
// grid 512 x 256 threads: block = (h,b), wave = tt (wave-parallel merge).
__global__ __launch_bounds__(256) void k_merge(
    const unsigned short* __restrict__ qws, const float* __restrict__ knew,
    const float* __restrict__ vnew, const float* __restrict__ mask,
    const float* __restrict__ Opart, const float* __restrict__ mpart,
    const float* __restrict__ lpart, unsigned short* __restrict__ attn) {
  const int bx = blockIdx.x;
  const int h = bx & 31, b = bx >> 5;
  const int tt = threadIdx.x >> 6;
  const int d = threadIdx.x & 63;
  const int r = b * 4 + tt;
  float qd = bs2f(qws[h * 4608 + r * 72 + d]);
  float scn[4];
  #pragma unroll
  for (int tp = 0; tp < 4; ++tp) {
    float kn = knew[((h * 16 + b) * 4 + tp) * 64 + d];
    float s = wave_sum(qd * kn);
    s += mask[(size_t)r * 4100 + 4096 + tp];
    scn[tp] = fmaxf(s, NEG_HUGE);
  }
  float mi[16], li[16];
  float mtot = NEG_HUGE;
  #pragma unroll
  for (int i = 0; i < 16; ++i) {
    mi[i] = mpart[(h * 16 + i) * 64 + r];
    li[i] = lpart[(h * 16 + i) * 64 + r];
    mtot = fmaxf(mtot, mi[i]);
  }
  #pragma unroll
  for (int tp = 0; tp < 4; ++tp) mtot = fmaxf(mtot, scn[tp]);
  float ltot = 0.f, od = 0.f;
  #pragma unroll
  for (int i = 0; i < 16; ++i) {
    float fct = __expf(mi[i] - mtot);
    ltot += li[i] * fct;
    od += Opart[((size_t)(h * 16 + i) * 64 + r) * 64 + d] * fct;
  }
  #pragma unroll
  for (int tp = 0; tp < 4; ++tp) {
    float e = __expf(scn[tp] - mtot);
    ltot += e;
    od += e * vnew[((h * 16 + b) * 4 + tp) * 64 + d];
  }
  attn[(size_t)r * 2048 + h * 64 + d] = f2bs(od / ltot);
}

// -------------- Kernel 5: output projection, split-K partials ----------------
// grid (32, 8): x = 64-col block, y = k-split (256 k each), LDS-staged A.
__global__ __launch_bounds__(256) void k_out(
    const unsigned short* __restrict__ attn, const float* __restrict__ Wo,
    float* __restrict__ part) {
  __shared__ __align__(16) unsigned short As[64 * 264];
  const int n0 = blockIdx.x * 64;
  const int ksb = blockIdx.y;
  const int k0 = ksb * 256;
  const int t = threadIdx.x, lane = t & 63, w = t >> 6;
  const int cl = lane & 15, quad = lane >> 4;
  #pragma unroll
  for (int i = 0; i < 8; ++i) {
    int idx8 = t + (i << 8);          // 0..2047 short8s
    int row = idx8 >> 5;
    int col = (idx8 & 31) << 3;
    *reinterpret_cast<uint4*>(&As[row * 264 + col]) =
        *reinterpret_cast<const uint4*>(attn + (size_t)row * 2048 + k0 + col);
  }
  __syncthreads();
  f4 acc[4];
  #pragma unroll
  for (int i = 0; i < 4; ++i) acc[i] = fzero();
  const int cw = n0 + w * 16 + cl;
  const float* wbase = Wo + (size_t)cw * 2048 + k0;
  #pragma unroll
  for (int ks2 = 0; ks2 < 8; ++ks2) {
    const int kb = ks2 * 32 + quad * 8;
    f4 w0 = *reinterpret_cast<const f4*>(wbase + kb);
    f4 w1 = *reinterpret_cast<const f4*>(wbase + kb + 4);
    s8v bf = cvt8(w0, w1);
    #pragma unroll
    for (int mt = 0; mt < 4; ++mt) {
      s8v af = *reinterpret_cast<const s8v*>(&As[(mt * 16 + cl) * 264 + kb]);
      acc[mt] = mfma16(af, bf, acc[mt]);
    }
  }
  float* op = part + (size_t)ksb * 131072;
  #pragma unroll
  for (int mt = 0; mt < 4; ++mt)
    #pragma unroll
    for (int rg = 0; rg < 4; ++rg) {
      int r = mt * 16 + quad * 4 + rg;
      op[r * 2048 + n0 + w * 16 + cl] = acc[mt][rg];
    }
}

// ------------- Kernel 6: reduce 8 + bias -> f32 output (vectorized) ----------
__global__ __launch_bounds__(256) void k_out_red(
    const float* __restrict__ part, const float* __restrict__ bo,
    float* __restrict__ out) {
  const int i4 = blockIdx.x * 256 + threadIdx.x;   // < 32768 float4s
  f4 s = *reinterpret_cast<const f4*>(part + (size_t)i4 * 4);
  #pragma unroll
  for (int ks = 1; ks < 8; ++ks) {
    f4 p2 = *reinterpret_cast<const f4*>(part + (size_t)ks * 131072 + (size_t)i4 * 4);
    #pragma unroll
    for (int j = 0; j < 4; ++j) s[j] += p2[j];
  }
  f4 bias = *reinterpret_cast<const f4*>(bo + (i4 & 511) * 4);
  f4 o;
  #pragma unroll
  for (int j = 0; j < 4; ++j) o[j] = s[j] + bias[j];
  *reinterpret_cast<f4*>(out + (size_t)i4 * 4) = o;
}

extern "C" void kernel_launch(void* const* d_in, const int* in_sizes, int n_in,
                              void* d_out, int out_size, void* d_ws, size_t ws_size,
                              hipStream_t stream) {
  const float* hs   = (const float*)d_in[0];
  const float* pk   = (const float*)d_in[1];
  const float* pv   = (const float*)d_in[2];
  const float* mask = (const float*)d_in[3];
  const float* Wq   = (const float*)d_in[4];
  const float* bq   = (const float*)d_in[5];
  const float* Wk   = (const float*)d_in[6];
  const float* bk   = (const float*)d_in[7];
  const float* Wv   = (const float*)d_in[8];
  const float* bv   = (const float*)d_in[9];
  const float* Wo   = (const float*)d_in[10];
  const float* bo   = (const float*)d_in[11];

  float* f = (float*)d_ws;
  float* qkv_part = f;                       // [8][64][6144]
  float* o_part   = qkv_part + 3145728;      // [8][64][2048]
  float* Opart    = o_part   + 1048576;      // [32][16][64][64]
  float* mpart    = Opart    + 2097152;      // [32][16][64]
  float* lpart    = mpart    + 32768;
  float* knew     = lpart    + 32768;        // [32][16][4][64]
  float* vnew     = knew     + 131072;
  unsigned short* qws  = (unsigned short*)(vnew + 131072);  // [32][64][72] bf16
  unsigned short* attn = qws + 147456;                      // [64][2048] bf16

  k_qkv<<<dim3(96, 8), 256, 0, stream>>>(hs, Wq, Wk, Wv, qkv_part);
  k_qkv_red<<<384, 256, 0, stream>>>(qkv_part, bq, bk, bv, qws, knew, vnew);
  k_flash<<<512, 256, 0, stream>>>(qws, pk, pv, mask, Opart, mpart, lpart);
  k_merge<<<512, 256, 0, stream>>>(qws, knew, vnew, mask, Opart, mpart, lpart, attn);
  k_out<<<dim3(32, 8), 256, 0, stream>>>(attn, Wo, o_part);
  k_out_red<<<128, 256, 0, stream>>>(o_part, bo, (float*)d_out);
}